// Round 12
// baseline (174.543 us; speedup 1.0000x reference)
//
#include <hip/hip_runtime.h>
#include <hip/hip_bf16.h>
#include <stdint.h>

#define BATCH 4096
#define KGRP  8
#define BLK   1024
#define TOTAL 8192

typedef __attribute__((ext_vector_type(8))) short short8;
typedef __attribute__((ext_vector_type(4))) float f32x4;

#define AS1 __attribute__((address_space(1)))
#define AS3 __attribute__((address_space(3)))

// ---------- helpers ----------

__device__ __forceinline__ unsigned short f2bf(float f) {
    union { float f; uint32_t u; } c; c.f = f;
    uint32_t u = c.u;
    u += 0x7fffu + ((u >> 16) & 1u);   // round-to-nearest-even
    return (unsigned short)(u >> 16);
}

__device__ __forceinline__ float fast_tanh(float x) {
    float e = __expf(2.0f * x);
    return 1.0f - 2.0f / (e + 1.0f);
}

__device__ __forceinline__ void gload16(const unsigned short* src, char* dst) {
    __builtin_amdgcn_global_load_lds((const AS1 uint32_t*)src, (AS3 uint32_t*)dst, 16, 0, 0);
}

template<int N> __device__ __forceinline__ void waitvm() {
    if constexpr (N == 0)      asm volatile("s_waitcnt vmcnt(0)" ::: "memory");
    else if constexpr (N == 2) asm volatile("s_waitcnt vmcnt(2)" ::: "memory");
    else if constexpr (N == 4) asm volatile("s_waitcnt vmcnt(4)" ::: "memory");
    else if constexpr (N == 6) asm volatile("s_waitcnt vmcnt(6)" ::: "memory");
}

// ---------- prep: W f32 -> bf16 (80 MB traffic, ~8 us) ----------

__global__ void k_wcast(const float4* __restrict__ W, ushort4* __restrict__ Wb) {
    const int n4 = KGRP * BLK * BLK / 4;
    for (int i = blockIdx.x * 256 + threadIdx.x; i < n4; i += 1024 * 256) {
        float4 f = W[i];
        ushort4 o;
        o.x = f2bf(f.x); o.y = f2bf(f.y); o.z = f2bf(f.z); o.w = f2bf(f.w);
        Wb[i] = o;
    }
}

// ---------- fused GEMM: r7 skeleton + tanh fused into A staging ----------
// Block = 128x256 of group g, 8 waves (2M x 4N, wave 64x64), BK=32, dbuf 2x24576.
// A: v -> regs (2-tile-deep f32 pipeline) -> tanh -> bf16 -> swizzled ds_write.
// B: gload_lds DMA from pre-cast Wb (pre-swizzled source), counted vmcnt.
// Swizzle both sides (r4-r9 verified): phys16Bslot = logslot ^ ((row>>1)&3).
//
// VMEM issue order per steady tile kt: [ph0: vload(kt+3) 2 instr][ph1: Bdma(kt+2)
// 2 instr]; sched_barrier(0) at each boundary confines them to their tile.
// Boundary of kt guards B(kt+1) (issued at kt-1): newer = vload@kt(2)+Bdma@kt(2)
// -> vmcnt(4). Tails: kt=29 -> vmcnt(2) (no vload); kt=30 -> vmcnt(0); kt=31 none.
// (r3 lesson: counts stay exact when staging stops.)
// A-write hazard: ds_write A(kt+1) -> buf^1, whose readers (tile kt-1) all passed
// the kt-1 boundary barrier; lgkmcnt(0) before each boundary publishes the write.
// B-region DMA at ph1 targets cur's B region, consumed at ph0 (reads retired
// before ph0-end barrier via MFMA consumption).

template<bool WRA, bool ISSV, bool ISSB, int W>
__device__ __forceinline__ void tile_f(int kt, char* ldsp,
                                       uint32_t aRd, uint32_t bRd, uint32_t aWr,
                                       const float* vsrc, const unsigned short* BsrcT,
                                       uint32_t sdstB,
                                       float4& vc0, float4& vc1,
                                       f32x4 (*acc)[4]) {
    const uint32_t cur = (uint32_t)(kt & 1) * 24576u;
    const uint32_t oth = cur ^ 24576u;
    const char* Lb = ldsp + cur;

    short8 bfr[4], am[2];

    // ---- ph0: read B all + A m0,m1; write A(kt+1); issue v(kt+3) ----
#pragma unroll
    for (int n = 0; n < 4; ++n)
        bfr[n] = *(const short8*)(Lb + bRd + n * 1024);
#pragma unroll
    for (int i = 0; i < 2; ++i)
        am[i] = *(const short8*)(Lb + aRd + i * 1024);
    if constexpr (WRA) {
        short8 p;
        p[0] = (short)f2bf(fast_tanh(vc0.x)); p[1] = (short)f2bf(fast_tanh(vc0.y));
        p[2] = (short)f2bf(fast_tanh(vc0.z)); p[3] = (short)f2bf(fast_tanh(vc0.w));
        p[4] = (short)f2bf(fast_tanh(vc1.x)); p[5] = (short)f2bf(fast_tanh(vc1.y));
        p[6] = (short)f2bf(fast_tanh(vc1.z)); p[7] = (short)f2bf(fast_tanh(vc1.w));
        *(short8*)(ldsp + oth + aWr) = p;
    }
    if constexpr (ISSV) {   // refill the just-consumed pair with v(kt+3)
        vc0 = *(const float4*)(vsrc + (kt + 3) * 32);
        vc1 = *(const float4*)(vsrc + (kt + 3) * 32 + 4);
    }
    __builtin_amdgcn_s_setprio(1);
#pragma unroll
    for (int i = 0; i < 2; ++i)
#pragma unroll
        for (int n = 0; n < 4; ++n)
            acc[i][n] = __builtin_amdgcn_mfma_f32_16x16x32_bf16(am[i], bfr[n], acc[i][n], 0, 0, 0);
    __builtin_amdgcn_s_setprio(0);
    __builtin_amdgcn_s_barrier();
    __builtin_amdgcn_sched_barrier(0);

    // ---- ph1: read A m2,m3; DMA B(kt+2) ----
#pragma unroll
    for (int i = 0; i < 2; ++i)
        am[i] = *(const short8*)(Lb + aRd + (2 + i) * 1024);
    if constexpr (ISSB) {
        gload16(BsrcT + (size_t)(kt + 2) * 32, ldsp + cur + 8192u + sdstB);
        gload16(BsrcT + (size_t)128 * BLK + (size_t)(kt + 2) * 32, ldsp + cur + 16384u + sdstB);
    }
    __builtin_amdgcn_s_setprio(1);
#pragma unroll
    for (int i = 0; i < 2; ++i)
#pragma unroll
        for (int n = 0; n < 4; ++n)
            acc[2 + i][n] = __builtin_amdgcn_mfma_f32_16x16x32_bf16(am[i], bfr[n], acc[2 + i][n], 0, 0, 0);
    __builtin_amdgcn_s_setprio(0);
    if constexpr (W >= 0) {
        asm volatile("s_waitcnt lgkmcnt(0)" ::: "memory");   // publish A ds_write
        waitvm<W>();
        __builtin_amdgcn_s_barrier();
        __builtin_amdgcn_sched_barrier(0);
    }
}

__global__ __launch_bounds__(512, 4)
void k_main(const float* __restrict__ v, const unsigned short* __restrict__ Wb,
            const float* __restrict__ x, const float* __restrict__ bias,
            float* __restrict__ out) {
    __shared__ __attribute__((aligned(1024))) char lds[49152];   // 2x24576; bounce reuses
    char* ldsp = lds;

    // XCD affinity: bid&7 == XCD; Wb[g] (2MB) L2-resident per XCD.
    const int bid   = blockIdx.x;              // 0..1023
    const int g     = bid & 7;
    const int slot  = bid >> 3;                // 0..127
    const int mtile = slot >> 2;               // 0..31
    const int ntile = slot & 3;                // 0..3
    const int gout  = (g + 1) & 7;

    const int tid  = threadIdx.x;
    const int lane = tid & 63;
    const int w    = tid >> 6;                 // 0..7
    const int wr   = w >> 2;                   // 0..1  (M)
    const int wc   = w & 3;                    // 0..3  (N)

    // ds_read swizzled column (r7-verified)
    const uint32_t kc  = ((uint32_t)((lane >> 4) ^ ((lane >> 1) & 3))) << 4;
    const uint32_t aRd = (uint32_t)(wr * 64 + (lane & 15)) * 64u + kc;            // A @0
    const uint32_t bRd = 8192u + (uint32_t)(wc * 64 + (lane & 15)) * 64u + kc;    // B @8K

    // A ds_write: thread t -> row t>>2, log slot t&3, phys slot ^= (row>>1)&3
    const uint32_t aWr = (uint32_t)(tid >> 2) * 64u +
                         (((uint32_t)((tid & 3) ^ ((tid >> 3) & 3))) << 4);
    // v source: row mtile*128 + (t>>2), elems (t&3)*8 (+kt*32 per tile)
    const float* vsrc = v + (size_t)(mtile * 128 + (tid >> 2)) * TOTAL
                          + (size_t)g * BLK + (tid & 3) * 8;

    // B staging source pre-swizzle (r7-verified)
    const int sColB = ((lane & 3) ^ ((lane >> 3) & 3)) << 3;
    const unsigned short* BsrcT = Wb + (size_t)g * BLK * BLK
                                     + (size_t)(ntile * 256 + w * 16 + (lane >> 2)) * BLK + sColB;
    const uint32_t sdstB = (uint32_t)(w << 10);

    f32x4 acc[4][4];
#pragma unroll
    for (int m = 0; m < 4; ++m)
#pragma unroll
        for (int n = 0; n < 4; ++n) acc[m][n] = (f32x4){0.f, 0.f, 0.f, 0.f};

    // prologue: Bdma(0)->buf0, Bdma(1)->buf1; A(0) direct write; vA=v(1), vB=v(2)
    gload16(BsrcT, ldsp + 8192u + sdstB);
    gload16(BsrcT + (size_t)128 * BLK, ldsp + 16384u + sdstB);
    gload16(BsrcT + 32, ldsp + 24576u + 8192u + sdstB);
    gload16(BsrcT + (size_t)128 * BLK + 32, ldsp + 24576u + 16384u + sdstB);
    float4 t0a = *(const float4*)(vsrc);
    float4 t0b = *(const float4*)(vsrc + 4);
    float4 vA0 = *(const float4*)(vsrc + 32), vA1 = *(const float4*)(vsrc + 36);
    float4 vB0 = *(const float4*)(vsrc + 64), vB1 = *(const float4*)(vsrc + 68);
    {
        short8 p;
        p[0] = (short)f2bf(fast_tanh(t0a.x)); p[1] = (short)f2bf(fast_tanh(t0a.y));
        p[2] = (short)f2bf(fast_tanh(t0a.z)); p[3] = (short)f2bf(fast_tanh(t0a.w));
        p[4] = (short)f2bf(fast_tanh(t0b.x)); p[5] = (short)f2bf(fast_tanh(t0b.y));
        p[6] = (short)f2bf(fast_tanh(t0b.z)); p[7] = (short)f2bf(fast_tanh(t0b.w));
        *(short8*)(ldsp + aWr) = p;
    }
    asm volatile("s_waitcnt lgkmcnt(0)" ::: "memory");
    waitvm<6>();                               // B(0) landed (newer: B(1)2 + vA2 + vB2)
    __builtin_amdgcn_s_barrier();
    __builtin_amdgcn_sched_barrier(0);

    // K loop: even tiles consume/refill vA, odd vB (2-tile-deep v pipeline)
#pragma unroll 1
    for (int k2 = 0; k2 < 14; ++k2) {
        tile_f<true, true, true, 4>(2 * k2,     ldsp, aRd, bRd, aWr, vsrc, BsrcT, sdstB, vA0, vA1, acc);
        tile_f<true, true, true, 4>(2 * k2 + 1, ldsp, aRd, bRd, aWr, vsrc, BsrcT, sdstB, vB0, vB1, acc);
    }
    tile_f<true, true,  true,  4>(28, ldsp, aRd, bRd, aWr, vsrc, BsrcT, sdstB, vA0, vA1, acc);
    tile_f<true, false, true,  2>(29, ldsp, aRd, bRd, aWr, vsrc, BsrcT, sdstB, vB0, vB1, acc);
    tile_f<true, false, false, 0>(30, ldsp, aRd, bRd, aWr, vsrc, BsrcT, sdstB, vA0, vA1, acc);
    tile_f<false, false, false, -1>(31, ldsp, aRd, bRd, aWr, vsrc, BsrcT, sdstB, vB0, vB1, acc);

    // all waves done with K-loop LDS before the bounce reuses it
    __builtin_amdgcn_s_barrier();

    // ---------------- epilogue: out = x + bias + acc (r7-verified bounce) ----
    // acc C/D mapping (m89/m91): col = lane&15, row = (lane>>4)*4 + j.
    const int q  = lane >> 4;
    const int cl = lane & 15;
    const int row0 = mtile * 128 + wr * 64;
    const int col0 = ntile * 256 + wc * 64;    // within group
    char* eb = ldsp + (uint32_t)w * 4352u;
    const float4 bias4 = *(const float4*)&bias[g * BLK + col0 + cl * 4];

#pragma unroll
    for (int m = 0; m < 4; ++m) {
#pragma unroll
        for (int n = 0; n < 4; ++n)
#pragma unroll
            for (int j = 0; j < 4; ++j)
                *(float*)(eb + (q * 4 + j) * 272 + (n * 16 + cl) * 4) = acc[m][n][j];
        asm volatile("s_waitcnt lgkmcnt(0)" ::: "memory");
        __builtin_amdgcn_sched_barrier(0);
#pragma unroll
        for (int i = 0; i < 4; ++i) {
            f32x4 vv = *(const f32x4*)(eb + (q + 4 * i) * 272 + cl * 16);
            const int r = row0 + m * 16 + q + 4 * i;
            const size_t idx = (size_t)r * TOTAL + (size_t)gout * BLK + col0 + cl * 4;
            const float4 xv = *(const float4*)&x[idx];
            float4 o;
            o.x = xv.x + bias4.x + vv[0];
            o.y = xv.y + bias4.y + vv[1];
            o.z = xv.z + bias4.z + vv[2];
            o.w = xv.w + bias4.w + vv[3];
            *(float4*)&out[idx] = o;
        }
        asm volatile("s_waitcnt lgkmcnt(0)" ::: "memory");
        __builtin_amdgcn_sched_barrier(0);
    }
}

// ---------- fallback (ws too small): correct but slow ----------

__global__ void k_naive(const float* __restrict__ x, const float* __restrict__ v,
                        const float* __restrict__ W, const float* __restrict__ b,
                        float* __restrict__ out) {
    __shared__ float hv[BLK];
    const int bid = blockIdx.x;
    const int quarter = bid & 3;
    const int g = (bid >> 2) & 7;
    const int row = bid >> 5;
    for (int i = threadIdx.x; i < BLK; i += 256)
        hv[i] = tanhf(v[(size_t)row * TOTAL + g * BLK + i]);
    __syncthreads();
    const int o = quarter * 256 + threadIdx.x;
    const float* wrow = W + ((size_t)g * BLK + o) * BLK;
    float s = 0.f;
    for (int i = 0; i < BLK; ++i) s += hv[i] * wrow[i];
    const size_t oi = (size_t)row * TOTAL + (size_t)((g + 1) & 7) * BLK + o;
    out[oi] = x[oi] + b[g * BLK + o] + s;
}

// ---------- launch ----------

extern "C" void kernel_launch(void* const* d_in, const int* in_sizes, int n_in,
                              void* d_out, int out_size, void* d_ws, size_t ws_size,
                              hipStream_t stream) {
    const float* x = (const float*)d_in[0];
    const float* v = (const float*)d_in[1];
    const float* W = (const float*)d_in[2];
    const float* b = (const float*)d_in[3];
    float* out = (float*)d_out;

    const size_t needW = (size_t)KGRP * BLK * BLK * sizeof(unsigned short);   // 16 MB

    if (ws_size >= needW) {
        unsigned short* Wb = (unsigned short*)d_ws;
        k_wcast<<<1024, 256, 0, stream>>>((const float4*)W, (ushort4*)Wb);
        k_main<<<1024, 512, 0, stream>>>(v, Wb, x, b, out);
    } else {
        k_naive<<<BATCH * KGRP * 4, 256, 0, stream>>>(x, v, W, b, out);
    }
}